// Round 11
// baseline (55.834 us; speedup 1.0000x reference)
//
#include <hip/hip_runtime.h>
#include <hip/hip_bf16.h>
#include <stdint.h>

typedef __attribute__((ext_vector_type(8))) short bf16x8;
typedef __attribute__((ext_vector_type(16))) float f32x16;
using bf16 = __hip_bfloat16;

static constexpr int Mdim = 512;   // A batch
static constexpr int Ndim = 64;    // B batch
static constexpr int Cdim = 128;   // channels (K of the GEMM)
static constexpr int Pdim = 64;    // H*W positions
static constexpr float EPS_ADD = 0.001f;

#define SB0 __builtin_amdgcn_sched_barrier(0)

// ---------------------------------------------------------------------------
// prep (fused): blocks 0..511 do prep_A (one m each); 512..767 do prep_G.
// Both outputs are written in MFMA-FRAGMENT ORDER so the gemm kernel's
// global loads are fully coalesced (1KB per wave-load):
//   A-tile (per m, 8192 elems): idx = h*4096 + ks*512 + lane*8 + e
//     where p = h*32 + (lane&31), c = ks*16 + (lane>>5)*8 + e
//   G-tile (per n, 8192 elems): idx = qt*4096 + ks*512 + lane*8 + e
//     where q = qt*32 + (lane&31), c = ks*16 + (lane>>5)*8 + e
// ---------------------------------------------------------------------------
__global__ void prep_kernel(const float* __restrict__ A, const float* __restrict__ B,
                            const float* __restrict__ Wg,
                            bf16* __restrict__ Afrag, bf16* __restrict__ Gfrag) {
    __shared__ float lds[128 * 65];
    const int t = threadIdx.x;

    if (blockIdx.x < 512) {
        const int m = blockIdx.x;
        const float* __restrict__ Am = A + (size_t)m * (Cdim * Pdim);
#pragma unroll
        for (int i = 0; i < 8; ++i) {
            int v = t + i * 256;
            int gidx = v * 4;
            int c = gidx >> 6, p = gidx & 63;
            float4 val = *reinterpret_cast<const float4*>(Am + gidx);
            float* dst = &lds[c * 65 + p];
            dst[0] = val.x; dst[1] = val.y; dst[2] = val.z; dst[3] = val.w;
        }
        __syncthreads();

        unsigned* __restrict__ dst32 = (unsigned*)(Afrag + (size_t)m * 8192);
#pragma unroll
        for (int i = 0; i < 16; ++i) {
            int pr = t + i * 256;            // 0..4095 pair index
            int p = pr >> 6;
            int c = (pr & 63) << 1;          // even c
            float f0 = lds[c * 65 + p];
            float f1 = lds[(c + 1) * 65 + p];
            union { bf16 hh[2]; unsigned u; } pk;
            pk.hh[0] = __float2bfloat16(f0);
            pk.hh[1] = __float2bfloat16(f1);
            int h = p >> 5, l31 = p & 31;
            int ks = c >> 4, hi = (c >> 3) & 1, e = c & 7;
            dst32[h * 2048 + ks * 256 + hi * 128 + l31 * 4 + (e >> 1)] = pk.u;
        }
    } else {
        const int nb = blockIdx.x - 512;
        const int n  = nb >> 2;
        const int q0 = (nb & 3) * 16;
        const float* __restrict__ Bn = B + (size_t)n * (Cdim * Pdim);
#pragma unroll
        for (int i = 0; i < 8; ++i) {
            int v = t + i * 256;
            int gidx = v * 4;
            int c = gidx >> 6, q = gidx & 63;
            float4 val = *reinterpret_cast<const float4*>(Bn + gidx);
            float* dst = &lds[c * 65 + q];
            dst[0] = val.x; dst[1] = val.y; dst[2] = val.z; dst[3] = val.w;
        }
        __syncthreads();

        const int d  = t & 127;
        const int qb = q0 + (t >> 7) * 8;
        float acc[8] = {0.f, 0.f, 0.f, 0.f, 0.f, 0.f, 0.f, 0.f};
        for (int c = 0; c < 128; ++c) {
            float w = Wg[c * 128 + d];
#pragma unroll
            for (int qi = 0; qi < 8; ++qi)
                acc[qi] = fmaf(lds[c * 65 + qb + qi], w, acc[qi]);
        }
        bf16* __restrict__ gdst = Gfrag + (size_t)n * 8192;
        const int ks = d >> 4, hi = (d >> 3) & 1, e = d & 7;
#pragma unroll
        for (int qi = 0; qi < 8; ++qi) {
            int q = qb + qi;
            int qt = q >> 5, l31 = q & 31;
            gdst[qt * 4096 + ks * 512 + hi * 256 + l31 * 8 + e] = __float2bfloat16(acc[qi]);
        }
    }
}

// ---------------------------------------------------------------------------
// gemm_max v9: NO LDS, NO barriers, register-direct fragment streams.
// Block = 256 thr (4 waves), wave (nw,h): n = bn*2+nw, p-half h.
//  - gf[2][8] loaded once (coalesced, fragment-ordered Gfrag).
//  - A: 8 coalesced 1KB loads/step into register dbuf (named aA/aB, fully
//    unrolled -> static indexing); prefetch next step before compute.
//  - 16 MFMA 32x32x16 per step; epilogue: 31 in-lane fmax + shfl_xor(32) +
//    coalesced 128B store (C/D layout verified in v8: col=lane&31=p,
//    row=(reg&3)+8*(reg>>2)+4*hi=q).
//  - Stagger: phase = bn&15 de-correlates the 32 blocks sharing an A-group.
// bid = bn*32+mg -> bid%8 = mg%8: same-A blocks share an XCD L2.
// VGPR: gf 64 + aA/aB 64 + acc 32 + addr ~30 -> ~190 (256,2 budget: 256).
// ---------------------------------------------------------------------------
__global__ __launch_bounds__(256, 2)
void gemm_max_kernel(const bf16* __restrict__ Afrag, const bf16* __restrict__ Gfrag,
                     float* __restrict__ out) {
    const int tid  = threadIdx.x;
    const int lane = tid & 63;
    const int w    = tid >> 6;            // 0..3
    const int nw = w >> 1, h = w & 1;
    const int l31 = lane & 31, hi = lane >> 5;
    const int mg = blockIdx.x & 31;       // 32 m-groups of 16 m's
    const int bn = blockIdx.x >> 5;       // 32 n-pairs
    const int n  = bn * 2 + nw;
    const int phase = bn & 15;

    // ---- G fragments: 16 coalesced 1KB loads, resident all 16 steps ----
    bf16x8 gf[2][8];
    {
        const bf16* Gp = Gfrag + (size_t)n * 8192 + lane * 8;
#pragma unroll
        for (int qt = 0; qt < 2; ++qt)
#pragma unroll
            for (int ks = 0; ks < 8; ++ks)
                gf[qt][ks] = *reinterpret_cast<const bf16x8*>(Gp + qt * 4096 + ks * 512);
    }

    const bf16* Ab = Afrag + (size_t)mg * 16 * 8192 + h * 4096 + lane * 8;
    auto loadA = [&](bf16x8 (&dst)[8], int se) {
        const bf16* p = Ab + (size_t)se * 8192;
#pragma unroll
        for (int ks = 0; ks < 8; ++ks)
            dst[ks] = *reinterpret_cast<const bf16x8*>(p + ks * 512);
    };

    f32x16 acc0, acc1;
    const f32x16 z16 = {0.f,0.f,0.f,0.f,0.f,0.f,0.f,0.f,0.f,0.f,0.f,0.f,0.f,0.f,0.f,0.f};

    auto compute = [&](const bf16x8 (&a)[8]) {
#pragma unroll
        for (int ks = 0; ks < 8; ++ks) {
            acc0 = __builtin_amdgcn_mfma_f32_32x32x16_bf16(
                gf[0][ks], a[ks], ks == 0 ? z16 : acc0, 0, 0, 0);
            acc1 = __builtin_amdgcn_mfma_f32_32x32x16_bf16(
                gf[1][ks], a[ks], ks == 0 ? z16 : acc1, 0, 0, 0);
        }
    };

    auto epilogue = [&](int se) {
        // pairwise tree -> lets clang fuse into v_max3
        float v01 = fmaxf(acc0[0], acc0[1]);
#pragma unroll
        for (int j = 2; j < 16; ++j) v01 = fmaxf(v01, acc0[j]);
        float v23 = fmaxf(acc1[0], acc1[1]);
#pragma unroll
        for (int j = 2; j < 16; ++j) v23 = fmaxf(v23, acc1[j]);
        float v = fmaxf(v01, v23);
        v = fmaxf(v, __shfl_xor(v, 32));   // fold q-row halves (hi)
        if (hi == 0)
            out[(size_t)(mg * 16 + se) * 4096 + n * 64 + h * 32 + l31] =
                fmaxf(v, 0.f) + EPS_ADD;
    };

    bf16x8 aA[8], aB[8];
    loadA(aA, phase);

#pragma unroll
    for (int s = 0; s < 16; ++s) {
        const int se = (s + phase) & 15;
        const int sn = (s + 1 + phase) & 15;
        if ((s & 1) == 0) {
            if (s < 15) loadA(aB, sn);
            SB0;                       // prefetch issued before MFMA cluster
            compute(aA);
            epilogue(se);
        } else {
            if (s < 15) loadA(aA, sn);
            SB0;
            compute(aB);
            epilogue(se);
        }
    }
}

// ---------------------------------------------------------------------------
extern "C" void kernel_launch(void* const* d_in, const int* in_sizes, int n_in,
                              void* d_out, int out_size, void* d_ws, size_t ws_size,
                              hipStream_t stream) {
    const float* A  = (const float*)d_in[0];
    const float* B  = (const float*)d_in[1];
    const float* Wg = (const float*)d_in[2];
    float* out = (float*)d_out;

    bf16* Afrag = (bf16*)d_ws;                                      // 512 x 8192 bf16 = 8 MiB
    bf16* Gfrag = (bf16*)((char*)d_ws + (size_t)Mdim * Pdim * Cdim * sizeof(bf16)); // 64 x 8192 bf16

    prep_kernel<<<768, 256, 0, stream>>>(A, B, Wg, Afrag, Gfrag);
    gemm_max_kernel<<<1024, 256, 0, stream>>>(Afrag, Gfrag, out);   // 32 mg x 32 bn
}

// Round 12
// 46.078 us; speedup vs baseline: 1.2117x; 1.2117x over previous
//
#include <hip/hip_runtime.h>
#include <hip/hip_bf16.h>
#include <stdint.h>

typedef __attribute__((ext_vector_type(8))) short bf16x8;
typedef __attribute__((ext_vector_type(16))) float f32x16;
using bf16 = __hip_bfloat16;

static constexpr int Mdim = 512;   // A batch
static constexpr int Ndim = 64;    // B batch
static constexpr int Cdim = 128;   // channels (K of the GEMM)
static constexpr int Pdim = 64;    // H*W positions
static constexpr float EPS_ADD = 0.001f;

#define SB0 __builtin_amdgcn_sched_barrier(0)
#define WAITV(N) asm volatile("s_waitcnt vmcnt(" #N ")" ::: "memory")

// ---------------------------------------------------------------------------
// async global->LDS, 16B per lane
// ---------------------------------------------------------------------------
__device__ __forceinline__ void gll16(const void* gsrc, void* ldst) {
    const __attribute__((address_space(1))) unsigned int* g =
        (const __attribute__((address_space(1))) unsigned int*)gsrc;
    __attribute__((address_space(3))) unsigned int* l =
        (__attribute__((address_space(3))) unsigned int*)(uintptr_t)ldst;
    __builtin_amdgcn_global_load_lds(g, l, 16, 0, 0);
}

// ---------------------------------------------------------------------------
// prep (fused, UNCHANGED from v9 — verified): fragment-ordered outputs.
//   A-tile (per m): idx = h*4096 + ks*512 + lane*8 + e
//     p = h*32 + (lane&31), c = ks*16 + (lane>>5)*8 + e
//   G-tile (per n): idx = qt*4096 + ks*512 + lane*8 + e
//     q = qt*32 + (lane&31), c = ks*16 + (lane>>5)*8 + e
// ---------------------------------------------------------------------------
__global__ void prep_kernel(const float* __restrict__ A, const float* __restrict__ B,
                            const float* __restrict__ Wg,
                            bf16* __restrict__ Afrag, bf16* __restrict__ Gfrag) {
    __shared__ float lds[128 * 65];
    const int t = threadIdx.x;

    if (blockIdx.x < 512) {
        const int m = blockIdx.x;
        const float* __restrict__ Am = A + (size_t)m * (Cdim * Pdim);
#pragma unroll
        for (int i = 0; i < 8; ++i) {
            int v = t + i * 256;
            int gidx = v * 4;
            int c = gidx >> 6, p = gidx & 63;
            float4 val = *reinterpret_cast<const float4*>(Am + gidx);
            float* dst = &lds[c * 65 + p];
            dst[0] = val.x; dst[1] = val.y; dst[2] = val.z; dst[3] = val.w;
        }
        __syncthreads();

        unsigned* __restrict__ dst32 = (unsigned*)(Afrag + (size_t)m * 8192);
#pragma unroll
        for (int i = 0; i < 16; ++i) {
            int pr = t + i * 256;
            int p = pr >> 6;
            int c = (pr & 63) << 1;
            float f0 = lds[c * 65 + p];
            float f1 = lds[(c + 1) * 65 + p];
            union { bf16 hh[2]; unsigned u; } pk;
            pk.hh[0] = __float2bfloat16(f0);
            pk.hh[1] = __float2bfloat16(f1);
            int h = p >> 5, l31 = p & 31;
            int ks = c >> 4, hi = (c >> 3) & 1, e = c & 7;
            dst32[h * 2048 + ks * 256 + hi * 128 + l31 * 4 + (e >> 1)] = pk.u;
        }
    } else {
        const int nb = blockIdx.x - 512;
        const int n  = nb >> 2;
        const int q0 = (nb & 3) * 16;
        const float* __restrict__ Bn = B + (size_t)n * (Cdim * Pdim);
#pragma unroll
        for (int i = 0; i < 8; ++i) {
            int v = t + i * 256;
            int gidx = v * 4;
            int c = gidx >> 6, q = gidx & 63;
            float4 val = *reinterpret_cast<const float4*>(Bn + gidx);
            float* dst = &lds[c * 65 + q];
            dst[0] = val.x; dst[1] = val.y; dst[2] = val.z; dst[3] = val.w;
        }
        __syncthreads();

        const int d  = t & 127;
        const int qb = q0 + (t >> 7) * 8;
        float acc[8] = {0.f, 0.f, 0.f, 0.f, 0.f, 0.f, 0.f, 0.f};
        for (int c = 0; c < 128; ++c) {
            float w = Wg[c * 128 + d];
#pragma unroll
            for (int qi = 0; qi < 8; ++qi)
                acc[qi] = fmaf(lds[c * 65 + qb + qi], w, acc[qi]);
        }
        bf16* __restrict__ gdst = Gfrag + (size_t)n * 8192;
        const int ks = d >> 4, hi = (d >> 3) & 1, e = d & 7;
#pragma unroll
        for (int qi = 0; qi < 8; ++qi) {
            int q = qb + qi;
            int qt = q >> 5, l31 = q & 31;
            gdst[qt * 4096 + ks * 512 + hi * 256 + l31 * 8 + e] = __float2bfloat16(acc[qi]);
        }
    }
}

// ---------------------------------------------------------------------------
// gemm_max v10: A-resident-in-registers, G broadcast via LDS.
// Block = 4 waves; wave = one m, full A-tile (64 VGPR) held for the whole
// kernel. 16 n-steps: G-tile (16KB) staged into 2-buf LDS ping-pong; all
// waves read the full G with contiguous conflict-free ds_read_b128 (LDS
// broadcast: 512 FLOP per VMEM-issued byte at block level).
// Per CU-step (2 blocks/CU): 256 MFMA = 2048 cyc (binder), LDS-read 1024,
// VALU ~1200, VMEM 6 instr. MFMA-pipe-dominant by construction.
// Sync/step: WAITV(2) [drain stage(s), keep 2 stores] + raw s_barrier; then
// stage(s+1) into the buffer everyone provably finished reading (barrier),
// full-step (~2k cyc) latency cover. acc chains: 4 indep x 8 deep.
// MFMA 32x32x16, mfma(G, A, acc): D col = lane&31 = p, row = q (m74/m101);
// epilogue = 31 in-lane fmax + shfl_xor(32) + coalesced 128B store.
// Grid 512 = 128 mg x 4 bn -> exactly 2 blocks/CU, independent domains.
// ---------------------------------------------------------------------------
__global__ __launch_bounds__(256, 2)
void gemm_max_kernel(const bf16* __restrict__ Afrag, const bf16* __restrict__ Gfrag,
                     float* __restrict__ out) {
    __shared__ bf16 sG[2][8192];          // 2 x 16KB ping-pong, fragment order
    const int tid  = threadIdx.x;
    const int lane = tid & 63;
    const int wv   = tid >> 6;            // 0..3 -> m = mg*4 + wv
    const int l31 = lane & 31, hi = lane >> 5;
    const int mg = blockIdx.x & 127;      // 128 m-groups of 4
    const int bn = blockIdx.x >> 7;       // 4 n-groups of 16
    const int m  = mg * 4 + wv;

    // ---- A-tile resident: 16 coalesced 1KB loads (oldest vmcnt events) ----
    bf16x8 a[2][8];                       // [p-half h][ks]
    {
        const bf16* Ap = Afrag + (size_t)m * 8192 + lane * 8;
#pragma unroll
        for (int h = 0; h < 2; ++h)
#pragma unroll
            for (int ks = 0; ks < 8; ++ks)
                a[h][ks] = *reinterpret_cast<const bf16x8*>(Ap + h * 4096 + ks * 512);
    }
    asm volatile("" ::: "memory");        // pin A-loads before stage issues

    const char* Gsrc = (const char*)(Gfrag + (size_t)(bn * 16) * 8192);
    auto stageG = [&](int s) {            // 16KB: 4 x gll16 per thread
        char* dst = (char*)&sG[s & 1][0];
        const char* src = Gsrc + (size_t)s * 16384;
#pragma unroll
        for (int i = 0; i < 4; ++i) {
            int f = (i * 256 + tid) * 16;
            gll16(src + f, dst + f);
        }
    };
    stageG(0);

    f32x16 acc[2][2];                     // [qt][h]
    const f32x16 z16 = {0.f,0.f,0.f,0.f,0.f,0.f,0.f,0.f,0.f,0.f,0.f,0.f,0.f,0.f,0.f,0.f};

    auto compute = [&](int s) {
        const char* gb = (const char*)&sG[s & 1][0] + lane * 16;
        bf16x8 gf[2][8];                  // contiguous 1KB ds_read_b128 x16
#pragma unroll
        for (int qt = 0; qt < 2; ++qt)
#pragma unroll
            for (int ks = 0; ks < 8; ++ks)
                gf[qt][ks] = *reinterpret_cast<const bf16x8*>(gb + qt * 8192 + ks * 1024);
#pragma unroll
        for (int ks = 0; ks < 8; ++ks)
#pragma unroll
            for (int qt = 0; qt < 2; ++qt)
#pragma unroll
                for (int h = 0; h < 2; ++h)
                    acc[qt][h] = __builtin_amdgcn_mfma_f32_32x32x16_bf16(
                        gf[qt][ks], a[h][ks], ks == 0 ? z16 : acc[qt][h], 0, 0, 0);
    };

    auto epilogue = [&](int s) {
        const int ng = bn * 16 + s;
#pragma unroll
        for (int h = 0; h < 2; ++h) {
            float v = fmaxf(acc[0][h][0], acc[0][h][1]);
#pragma unroll
            for (int j = 2; j < 16; ++j) v = fmaxf(v, acc[0][h][j]);
#pragma unroll
            for (int j = 0; j < 16; ++j) v = fmaxf(v, acc[1][h][j]);
            v = fmaxf(v, __shfl_xor(v, 32));   // fold q hi-halves
            if (hi == 0)
                out[(size_t)m * 4096 + ng * 64 + h * 32 + l31] = fmaxf(v, 0.f) + EPS_ADD;
        }
    };

    // ---- step 0: drain A + G0 entirely ----
    WAITV(0); __builtin_amdgcn_s_barrier(); SB0;
    stageG(1);
    compute(0); epilogue(0); SB0;

    // ---- steps 1..15: WAITV(2) drains stage(s), keeps 2 stores ----
    for (int s = 1; s <= 15; ++s) {
        WAITV(2); __builtin_amdgcn_s_barrier(); SB0;
        if (s < 15) stageG(s + 1);
        compute(s); epilogue(s); SB0;
    }
}

// ---------------------------------------------------------------------------
extern "C" void kernel_launch(void* const* d_in, const int* in_sizes, int n_in,
                              void* d_out, int out_size, void* d_ws, size_t ws_size,
                              hipStream_t stream) {
    const float* A  = (const float*)d_in[0];
    const float* B  = (const float*)d_in[1];
    const float* Wg = (const float*)d_in[2];
    float* out = (float*)d_out;

    bf16* Afrag = (bf16*)d_ws;                                      // 512 x 8192 bf16 = 8 MiB
    bf16* Gfrag = (bf16*)((char*)d_ws + (size_t)Mdim * Pdim * Cdim * sizeof(bf16)); // 64 x 8192 bf16

    prep_kernel<<<768, 256, 0, stream>>>(A, B, Wg, Afrag, Gfrag);
    gemm_max_kernel<<<512, 256, 0, stream>>>(Afrag, Gfrag, out);   // 128 mg x 4 bn
}